// Round 1
// baseline (4634.629 us; speedup 1.0000x reference)
//
#include <hip/hip_runtime.h>

#define ENSN 256
#define XDIM 8192
#define YD 256
#define BATCH 8

// ws layout (float offsets)
#define OFF_Y   0          // [2048][256]            Y = Ens @ H
#define OFF_YC  524288     // [8][256(y)][256(e)]    Yc (transposed, centered)
#define OFF_AUG 1048576    // [8][256][512]          [A | innov] -> [U | M1]
#define OFF_W   2097152    // [8][256(f)][256(e)]    W = Yc^T M1 / 256
#define OFF_XM  2621440    // [8][8192]              x_m

// ---------------- K1: x_m[b][x] = mean_e Ens[b,e,x] ----------------
__global__ __launch_bounds__(256) void k1_colmean(const float* __restrict__ E,
                                                  float* __restrict__ xm) {
    int x = blockIdx.x * 256 + threadIdx.x;
    int b = blockIdx.y;
    const float* p = E + (size_t)b * ENSN * XDIM + x;
    float s = 0.f;
    #pragma unroll 8
    for (int e = 0; e < ENSN; e++) s += p[(size_t)e * XDIM];
    xm[b * XDIM + x] = s * (1.0f / ENSN);
}

// ---------------- K2: Y[r][y] += Ens[r][:] @ H[:][y], split-K=8 ----------------
// BM=32 rows, BN=256 (all cols), BK=16, 256 thr, TM=2, TN=16. grid (64, 8)
__global__ __launch_bounds__(256) void k2_ygemm(const float* __restrict__ E,
                                                const float* __restrict__ H,
                                                float* __restrict__ Y) {
    __shared__ float As[16][36];
    __shared__ float Bs[16][260];
    int tid = threadIdx.x;
    int m0 = blockIdx.x * 32;
    int kb0 = blockIdx.y * 1024;
    int tr = tid >> 4, tc = tid & 15;
    float acc[2][16];
    #pragma unroll
    for (int i = 0; i < 2; i++)
        #pragma unroll
        for (int j = 0; j < 16; j++) acc[i][j] = 0.f;
    int al = tid & 15, am = tid >> 4;
    for (int kb = kb0; kb < kb0 + 1024; kb += 16) {
        As[al][am]      = E[(size_t)(m0 + am) * XDIM + kb + al];
        As[al][am + 16] = E[(size_t)(m0 + am + 16) * XDIM + kb + al];
        #pragma unroll
        for (int p = 0; p < 16; p++)
            Bs[p][tid] = H[(kb + p) * YD + tid];
        __syncthreads();
        #pragma unroll
        for (int kk = 0; kk < 16; kk++) {
            float2 a  = *(const float2*)&As[kk][tr * 2];
            float4 b0 = *(const float4*)&Bs[kk][tc * 16];
            float4 b1 = *(const float4*)&Bs[kk][tc * 16 + 4];
            float4 b2 = *(const float4*)&Bs[kk][tc * 16 + 8];
            float4 b3 = *(const float4*)&Bs[kk][tc * 16 + 12];
            float bf[16] = {b0.x,b0.y,b0.z,b0.w, b1.x,b1.y,b1.z,b1.w,
                            b2.x,b2.y,b2.z,b2.w, b3.x,b3.y,b3.z,b3.w};
            #pragma unroll
            for (int j = 0; j < 16; j++) {
                acc[0][j] += a.x * bf[j];
                acc[1][j] += a.y * bf[j];
            }
        }
        __syncthreads();
    }
    #pragma unroll
    for (int i = 0; i < 2; i++)
        #pragma unroll
        for (int j = 0; j < 16; j++)
            atomicAdd(&Y[(m0 + tr * 2 + i) * YD + tc * 16 + j], acc[i][j]);
}

// ---------------- K3: y_m, Yc[y][e], innov -> aug right half ----------------
__global__ __launch_bounds__(256) void k3_center(const float* __restrict__ Y,
                                                 const float* __restrict__ ytm,
                                                 const float* __restrict__ ystd,
                                                 const float* __restrict__ noise,
                                                 float* __restrict__ Yc,
                                                 float* __restrict__ aug) {
    int b = blockIdx.x, tid = threadIdx.x;
    __shared__ float ym[256], tms[256], s2[256];
    __shared__ float T[64][65];
    float s = 0.f;
    for (int e = 0; e < ENSN; e++) s += Y[(b * ENSN + e) * YD + tid];
    ym[tid] = s * (1.0f / ENSN);
    tms[tid] = ytm[tid];
    float sd = ystd[tid];
    s2[tid] = sd * sd;
    __syncthreads();
    for (int y0 = 0; y0 < YD; y0 += 64)
        for (int e0 = 0; e0 < ENSN; e0 += 64) {
            int yc = tid & 63, g0 = tid >> 6;
            #pragma unroll
            for (int p = 0; p < 16; p++) {
                int er = g0 + p * 4;
                T[er][yc] = Y[(b * ENSN + e0 + er) * YD + y0 + yc];
            }
            __syncthreads();
            int ec = tid & 63;
            #pragma unroll
            for (int p = 0; p < 16; p++) {
                int yr = g0 + p * 4;
                int y = y0 + yr, e = e0 + ec;
                float yv = T[ec][yr] - ym[y];
                Yc[(size_t)b * YD * ENSN + y * ENSN + e] = yv;
                aug[(size_t)b * YD * 512 + y * 512 + 256 + e] =
                    tms[y] - yv + noise[(size_t)b * YD * ENSN + y * ENSN + e] * s2[y];
            }
            __syncthreads();
        }
}

// ---------------- K4: A = Yc Yc^T / 256 + diag(std^2) -> aug left half ----------------
__global__ __launch_bounds__(256) void k4_cyy(const float* __restrict__ Yc,
                                              const float* __restrict__ ystd,
                                              float* __restrict__ aug) {
    __shared__ float As[16][68];
    __shared__ float Bs[16][68];
    int tid = threadIdx.x;
    int m0 = blockIdx.x * 64, n0 = blockIdx.y * 64, b = blockIdx.z;
    const float* Ycb = Yc + (size_t)b * YD * ENSN;
    int tr = tid >> 4, tc = tid & 15;
    float acc[4][4];
    #pragma unroll
    for (int i = 0; i < 4; i++)
        #pragma unroll
        for (int j = 0; j < 4; j++) acc[i][j] = 0.f;
    int al = tid & 15, am0 = tid >> 4;
    for (int k0 = 0; k0 < ENSN; k0 += 16) {
        #pragma unroll
        for (int p = 0; p < 4; p++) {
            int am = am0 + p * 16;
            As[al][am] = Ycb[(m0 + am) * ENSN + k0 + al];
            Bs[al][am] = Ycb[(n0 + am) * ENSN + k0 + al];
        }
        __syncthreads();
        #pragma unroll
        for (int kk = 0; kk < 16; kk++) {
            float4 a = *(const float4*)&As[kk][tr * 4];
            float4 bb = *(const float4*)&Bs[kk][tc * 4];
            float af[4] = {a.x, a.y, a.z, a.w};
            float bf[4] = {bb.x, bb.y, bb.z, bb.w};
            #pragma unroll
            for (int i = 0; i < 4; i++)
                #pragma unroll
                for (int j = 0; j < 4; j++) acc[i][j] += af[i] * bf[j];
        }
        __syncthreads();
    }
    float* augb = aug + (size_t)b * YD * 512;
    #pragma unroll
    for (int i = 0; i < 4; i++) {
        int u = m0 + tr * 4 + i;
        #pragma unroll
        for (int j = 0; j < 4; j++) {
            int v = n0 + tc * 4 + j;
            float val = acc[i][j] * (1.0f / ENSN);
            if (u == v) { float sv = ystd[u]; val += sv * sv; }
            augb[u * 512 + v] = val;
        }
    }
}

// ---------------- K5: LU (no pivot, SPD) on [A|innov], then back-substitution ----------------
__global__ __launch_bounds__(1024) void k5_solve(float* __restrict__ aug) {
    int b = blockIdx.x, tid = threadIdx.x;
    float* A = aug + (size_t)b * YD * 512;
    __shared__ float piv[512];
    __shared__ float xs[256];
    // forward elimination on [A | innov]
    for (int k = 0; k < 256; k++) {
        if (tid < 512) piv[tid] = A[k * 512 + tid];
        __syncthreads();
        float ip = 1.0f / piv[k];
        int lane = tid & 63, rg = tid >> 6;  // 16 row groups x 64 lanes
        for (int i = k + 1 + rg; i < 256; i += 16) {
            float f = A[i * 512 + k] * ip;
            for (int j = k + 1 + lane; j < 512; j += 64)
                A[i * 512 + j] -= f * piv[j];
        }
        __syncthreads();
    }
    // backward substitution: U x = y  (y in right half) -> x in right half
    for (int k = 255; k >= 0; k--) {
        float invd = 1.0f / A[k * 512 + k];
        if (tid < 256) {
            float x = A[k * 512 + 256 + tid] * invd;
            A[k * 512 + 256 + tid] = x;
            xs[tid] = x;
        }
        __syncthreads();
        int lane = tid & 255, rg = tid >> 8;  // 4 row groups x 256 lanes
        for (int i = rg; i < k; i += 4) {
            float f = A[i * 512 + k];
            A[i * 512 + 256 + lane] -= f * xs[lane];
        }
        __syncthreads();
    }
}

// ---------------- K6: W[f][e] = sum_y Yc[y][f] * M1[y][e] / 256 ----------------
__global__ __launch_bounds__(256) void k6_w(const float* __restrict__ Yc,
                                            const float* __restrict__ aug,
                                            float* __restrict__ W) {
    __shared__ float As[16][68];
    __shared__ float Bs[16][68];
    int tid = threadIdx.x;
    int m0 = blockIdx.x * 64, n0 = blockIdx.y * 64, b = blockIdx.z;
    const float* Ycb = Yc + (size_t)b * YD * ENSN;
    const float* augb = aug + (size_t)b * YD * 512;
    int tr = tid >> 4, tc = tid & 15;
    float acc[4][4];
    #pragma unroll
    for (int i = 0; i < 4; i++)
        #pragma unroll
        for (int j = 0; j < 4; j++) acc[i][j] = 0.f;
    int c = tid & 63, kr0 = tid >> 6;
    for (int k0 = 0; k0 < YD; k0 += 16) {
        #pragma unroll
        for (int p = 0; p < 4; p++) {
            int kk = kr0 + p * 4;
            As[kk][c] = Ycb[(k0 + kk) * ENSN + m0 + c];       // A[m=f][k=y] = Yc[y][f]
            Bs[kk][c] = augb[(k0 + kk) * 512 + 256 + n0 + c]; // B[k=y][n=e] = M1[y][e]
        }
        __syncthreads();
        #pragma unroll
        for (int kk = 0; kk < 16; kk++) {
            float4 a = *(const float4*)&As[kk][tr * 4];
            float4 bb = *(const float4*)&Bs[kk][tc * 4];
            float af[4] = {a.x, a.y, a.z, a.w};
            float bf[4] = {bb.x, bb.y, bb.z, bb.w};
            #pragma unroll
            for (int i = 0; i < 4; i++)
                #pragma unroll
                for (int j = 0; j < 4; j++) acc[i][j] += af[i] * bf[j];
        }
        __syncthreads();
    }
    float* Wb = W + (size_t)b * ENSN * ENSN;
    #pragma unroll
    for (int i = 0; i < 4; i++)
        #pragma unroll
        for (int j = 0; j < 4; j++)
            Wb[(m0 + tr * 4 + i) * ENSN + n0 + tc * 4 + j] = acc[i][j] * (1.0f / ENSN);
}

// ---------------- K7: out[b,e,x] = Ens[b,e,x] + sum_f W[f][e]*(Ens[b,f,x]-x_m[b,x]) ----------------
// BM=256 (all e), BN=64 x, BK=16, 256 thr, TM=16, TN=4. grid (128, 8)
__global__ __launch_bounds__(256) void k7_update(const float* __restrict__ E,
                                                 const float* __restrict__ W,
                                                 const float* __restrict__ xm,
                                                 float* __restrict__ out) {
    __shared__ float As[16][260];
    __shared__ float Bs[16][68];
    __shared__ float xs[64];
    int tid = threadIdx.x;
    int x0 = blockIdx.x * 64;
    int b = blockIdx.y;
    const float* Wb = W + (size_t)b * ENSN * ENSN;
    const float* Eb = E + (size_t)b * ENSN * XDIM;
    if (tid < 64) xs[tid] = xm[b * XDIM + x0 + tid];
    __syncthreads();
    int tr = tid >> 4, tc = tid & 15;
    float acc[16][4];
    #pragma unroll
    for (int i = 0; i < 16; i++)
        #pragma unroll
        for (int j = 0; j < 4; j++) acc[i][j] = 0.f;
    for (int k0 = 0; k0 < ENSN; k0 += 16) {
        #pragma unroll
        for (int p = 0; p < 16; p++)
            As[p][tid] = Wb[(k0 + p) * ENSN + tid];  // As[k=f][m=e] = W[f][e]
        #pragma unroll
        for (int p = 0; p < 4; p++) {
            int kk = (tid >> 6) + p * 4;
            int cc = tid & 63;
            Bs[kk][cc] = Eb[(size_t)(k0 + kk) * XDIM + x0 + cc] - xs[cc];
        }
        __syncthreads();
        #pragma unroll
        for (int kk = 0; kk < 16; kk++) {
            float4 bv = *(const float4*)&Bs[kk][tc * 4];
            float bf[4] = {bv.x, bv.y, bv.z, bv.w};
            #pragma unroll
            for (int q = 0; q < 4; q++) {
                float4 av = *(const float4*)&As[kk][tr * 16 + q * 4];
                float af[4] = {av.x, av.y, av.z, av.w};
                #pragma unroll
                for (int c2 = 0; c2 < 4; c2++)
                    #pragma unroll
                    for (int j = 0; j < 4; j++)
                        acc[q * 4 + c2][j] += af[c2] * bf[j];
            }
        }
        __syncthreads();
    }
    #pragma unroll
    for (int i = 0; i < 16; i++) {
        int e = tr * 16 + i;
        size_t idx = (size_t)(b * ENSN + e) * XDIM + x0 + tc * 4;
        float4 ev = *(const float4*)&E[idx];
        float4 ov;
        ov.x = ev.x + acc[i][0];
        ov.y = ev.y + acc[i][1];
        ov.z = ev.z + acc[i][2];
        ov.w = ev.w + acc[i][3];
        *(float4*)&out[idx] = ov;
    }
}

extern "C" void kernel_launch(void* const* d_in, const int* in_sizes, int n_in,
                              void* d_out, int out_size, void* d_ws, size_t ws_size,
                              hipStream_t stream) {
    const float* Ens   = (const float*)d_in[0];  // [8,256,8192]
    const float* H     = (const float*)d_in[1];  // [8192,256]
    const float* ytm   = (const float*)d_in[2];  // [1,256]
    const float* ystd  = (const float*)d_in[3];  // [1,256]
    const float* noise = (const float*)d_in[4];  // [8,256,256]
    float* out = (float*)d_out;
    float* ws  = (float*)d_ws;

    float* Y   = ws + OFF_Y;
    float* Yc  = ws + OFF_YC;
    float* aug = ws + OFF_AUG;
    float* W   = ws + OFF_W;
    float* xm  = ws + OFF_XM;

    hipMemsetAsync(Y, 0, (size_t)2048 * 256 * sizeof(float), stream);

    k1_colmean<<<dim3(XDIM / 256, BATCH), 256, 0, stream>>>(Ens, xm);
    k2_ygemm<<<dim3(64, 8), 256, 0, stream>>>(Ens, H, Y);
    k3_center<<<dim3(BATCH), 256, 0, stream>>>(Y, ytm, ystd, noise, Yc, aug);
    k4_cyy<<<dim3(4, 4, BATCH), 256, 0, stream>>>(Yc, ystd, aug);
    k5_solve<<<dim3(BATCH), 1024, 0, stream>>>(aug);
    k6_w<<<dim3(4, 4, BATCH), 256, 0, stream>>>(Yc, aug, W);
    k7_update<<<dim3(XDIM / 64, BATCH), 256, 0, stream>>>(Ens, W, xm, out);
}

// Round 2
// 1336.482 us; speedup vs baseline: 3.4678x; 3.4678x over previous
//
#include <hip/hip_runtime.h>

#define ENSN 256
#define XDIM 8192
#define YD 256
#define BATCH 8

// ws layout (float offsets)
#define OFF_Y   0          // [2048][256]            Y = Ens @ H
#define OFF_YC  524288     // [8][256(y)][256(e)]    Yc (transposed, centered)
#define OFF_AUG 1048576    // [8][256][512]          [A | innov] -> [U | M1]
#define OFF_W   2097152    // [8][256(f)][256(e)]    W = Yc^T M1 / 256
#define OFF_XM  2621440    // [8][8192]              x_m

// ---------------- K1: x_m[b][x] = mean_e Ens[b,e,x] ----------------
__global__ __launch_bounds__(256) void k1_colmean(const float* __restrict__ E,
                                                  float* __restrict__ xm) {
    int x = blockIdx.x * 256 + threadIdx.x;
    int b = blockIdx.y;
    const float* p = E + (size_t)b * ENSN * XDIM + x;
    float s = 0.f;
    #pragma unroll 8
    for (int e = 0; e < ENSN; e++) s += p[(size_t)e * XDIM];
    xm[b * XDIM + x] = s * (1.0f / ENSN);
}

// ---------------- K2: Y[r][y] += Ens[r][:] @ H[:][y], split-K=8 ----------------
__global__ __launch_bounds__(256) void k2_ygemm(const float* __restrict__ E,
                                                const float* __restrict__ H,
                                                float* __restrict__ Y) {
    __shared__ float As[16][36];
    __shared__ float Bs[16][260];
    int tid = threadIdx.x;
    int m0 = blockIdx.x * 32;
    int kb0 = blockIdx.y * 1024;
    int tr = tid >> 4, tc = tid & 15;
    float acc[2][16];
    #pragma unroll
    for (int i = 0; i < 2; i++)
        #pragma unroll
        for (int j = 0; j < 16; j++) acc[i][j] = 0.f;
    int al = tid & 15, am = tid >> 4;
    for (int kb = kb0; kb < kb0 + 1024; kb += 16) {
        As[al][am]      = E[(size_t)(m0 + am) * XDIM + kb + al];
        As[al][am + 16] = E[(size_t)(m0 + am + 16) * XDIM + kb + al];
        #pragma unroll
        for (int p = 0; p < 16; p++)
            Bs[p][tid] = H[(kb + p) * YD + tid];
        __syncthreads();
        #pragma unroll
        for (int kk = 0; kk < 16; kk++) {
            float2 a  = *(const float2*)&As[kk][tr * 2];
            float4 b0 = *(const float4*)&Bs[kk][tc * 16];
            float4 b1 = *(const float4*)&Bs[kk][tc * 16 + 4];
            float4 b2 = *(const float4*)&Bs[kk][tc * 16 + 8];
            float4 b3 = *(const float4*)&Bs[kk][tc * 16 + 12];
            float bf[16] = {b0.x,b0.y,b0.z,b0.w, b1.x,b1.y,b1.z,b1.w,
                            b2.x,b2.y,b2.z,b2.w, b3.x,b3.y,b3.z,b3.w};
            #pragma unroll
            for (int j = 0; j < 16; j++) {
                acc[0][j] += a.x * bf[j];
                acc[1][j] += a.y * bf[j];
            }
        }
        __syncthreads();
    }
    #pragma unroll
    for (int i = 0; i < 2; i++)
        #pragma unroll
        for (int j = 0; j < 16; j++)
            atomicAdd(&Y[(m0 + tr * 2 + i) * YD + tc * 16 + j], acc[i][j]);
}

// ---------------- K3: y_m, Yc[y][e], innov -> aug right half ----------------
__global__ __launch_bounds__(256) void k3_center(const float* __restrict__ Y,
                                                 const float* __restrict__ ytm,
                                                 const float* __restrict__ ystd,
                                                 const float* __restrict__ noise,
                                                 float* __restrict__ Yc,
                                                 float* __restrict__ aug) {
    int b = blockIdx.x, tid = threadIdx.x;
    __shared__ float ym[256], tms[256], s2[256];
    __shared__ float T[64][65];
    float s = 0.f;
    for (int e = 0; e < ENSN; e++) s += Y[(b * ENSN + e) * YD + tid];
    ym[tid] = s * (1.0f / ENSN);
    tms[tid] = ytm[tid];
    float sd = ystd[tid];
    s2[tid] = sd * sd;
    __syncthreads();
    for (int y0 = 0; y0 < YD; y0 += 64)
        for (int e0 = 0; e0 < ENSN; e0 += 64) {
            int yc = tid & 63, g0 = tid >> 6;
            #pragma unroll
            for (int p = 0; p < 16; p++) {
                int er = g0 + p * 4;
                T[er][yc] = Y[(b * ENSN + e0 + er) * YD + y0 + yc];
            }
            __syncthreads();
            int ec = tid & 63;
            #pragma unroll
            for (int p = 0; p < 16; p++) {
                int yr = g0 + p * 4;
                int y = y0 + yr, e = e0 + ec;
                float yv = T[ec][yr] - ym[y];
                Yc[(size_t)b * YD * ENSN + y * ENSN + e] = yv;
                aug[(size_t)b * YD * 512 + y * 512 + 256 + e] =
                    tms[y] - yv + noise[(size_t)b * YD * ENSN + y * ENSN + e] * s2[y];
            }
            __syncthreads();
        }
}

// ---------------- K4: A = Yc Yc^T / 256 + diag(std^2) -> aug left half ----------------
__global__ __launch_bounds__(256) void k4_cyy(const float* __restrict__ Yc,
                                              const float* __restrict__ ystd,
                                              float* __restrict__ aug) {
    __shared__ float As[16][68];
    __shared__ float Bs[16][68];
    int tid = threadIdx.x;
    int m0 = blockIdx.x * 64, n0 = blockIdx.y * 64, b = blockIdx.z;
    const float* Ycb = Yc + (size_t)b * YD * ENSN;
    int tr = tid >> 4, tc = tid & 15;
    float acc[4][4];
    #pragma unroll
    for (int i = 0; i < 4; i++)
        #pragma unroll
        for (int j = 0; j < 4; j++) acc[i][j] = 0.f;
    int al = tid & 15, am0 = tid >> 4;
    for (int k0 = 0; k0 < ENSN; k0 += 16) {
        #pragma unroll
        for (int p = 0; p < 4; p++) {
            int am = am0 + p * 16;
            As[al][am] = Ycb[(m0 + am) * ENSN + k0 + al];
            Bs[al][am] = Ycb[(n0 + am) * ENSN + k0 + al];
        }
        __syncthreads();
        #pragma unroll
        for (int kk = 0; kk < 16; kk++) {
            float4 a = *(const float4*)&As[kk][tr * 4];
            float4 bb = *(const float4*)&Bs[kk][tc * 4];
            float af[4] = {a.x, a.y, a.z, a.w};
            float bf[4] = {bb.x, bb.y, bb.z, bb.w};
            #pragma unroll
            for (int i = 0; i < 4; i++)
                #pragma unroll
                for (int j = 0; j < 4; j++) acc[i][j] += af[i] * bf[j];
        }
        __syncthreads();
    }
    float* augb = aug + (size_t)b * YD * 512;
    #pragma unroll
    for (int i = 0; i < 4; i++) {
        int u = m0 + tr * 4 + i;
        #pragma unroll
        for (int j = 0; j < 4; j++) {
            int v = n0 + tc * 4 + j;
            float val = acc[i][j] * (1.0f / ENSN);
            if (u == v) { float sv = ystd[u]; val += sv * sv; }
            augb[u * 512 + v] = val;
        }
    }
}

// ---------------- K5: blocked LU (panel=32, LDS-resident) + backward subst ----------------
// grid = 8 (batch), 1024 threads. aug[b] is 256x512 [A | innov] -> [U | M1].
#define RST 516   // R panel stride (floats); row base 516*4B = 16B aligned
#define LST 232   // Ls stride, layout [k][row]
#define BST 296   // backward block stride: [U(32) | Z(256)] + pad

__global__ __launch_bounds__(1024) void k5_solve(float* __restrict__ aug) {
    __shared__ __align__(16) float R[32 * RST];   // 66 KB: panel rows x trailing cols
    __shared__ __align__(16) float Ls[32 * LST];  // 29.7 KB: L21 (transposed) / U-strip
    __shared__ float invd[32];
    int b = blockIdx.x, tid = threadIdx.x;
    float* A = aug + (size_t)b * 256 * 512;
    int ti = tid >> 5, tc = tid & 31;

    // ======== Phase A: blocked right-looking LU on [A | Z] ========
    for (int p = 0; p < 8; p++) {
        int c0 = 32 * p;
        int W = 512 - c0;               // trailing width incl RHS
        // load panel rows c0..c0+31, cols c0..511 into LDS
        for (int c = tc; c < W; c += 32)
            R[ti * RST + c] = A[(c0 + ti) * 512 + c0 + c];
        __syncthreads();
        // factor 32-row block, fused over ALL trailing cols (31 LDS steps)
        for (int j = 0; j < 31; j++) {
            if (ti > j) {
                float piv = R[j * RST + j];
                float f = R[ti * RST + j] / piv;
                for (int c = j + 1 + tc; c < W; c += 32)
                    R[ti * RST + c] -= f * R[j * RST + c];
            }
            __syncthreads();
        }
        if (tid < 32) invd[tid] = 1.0f / R[tid * RST + tid];
        __syncthreads();
        // write back U rows (incl transformed RHS)
        for (int c = tc; c < W; c += 32)
            A[(c0 + ti) * 512 + c0 + c] = R[ti * RST + c];
        // L21 = A21 * U11^-1 : row-parallel triangular solve (no barriers)
        int nb = 224 - c0;
        if (p < 7 && tid < nb) {
            int row = c0 + 32 + tid;
            const float* ap = A + row * 512 + c0;
            float l[32];
            #pragma unroll
            for (int j = 0; j < 32; j++) {
                float s = ap[j];
                #pragma unroll
                for (int m = 0; m < 32; m++)
                    if (m < j) s -= l[m] * R[m * RST + j];
                l[j] = s * invd[j];
            }
            #pragma unroll
            for (int k = 0; k < 32; k++)
                Ls[k * LST + tid] = l[k];
        }
        __syncthreads();
        // trailing update: A[c0+32.., c0+32..511] -= L21 * U12  (8x8 reg tiles)
        if (p < 7) {
            int nct = (W - 32) >> 3;           // col tiles
            int tiles = (nb >> 3) * nct;
            for (int t = tid; t < tiles; t += 1024) {
                int rt = t / nct, ct = t - rt * nct;
                int r0 = rt << 3, cc = 32 + (ct << 3);
                float* gp = A + (size_t)(c0 + 32 + r0) * 512 + c0 + cc;
                float4 acc[8][2];
                #pragma unroll
                for (int rr = 0; rr < 8; rr++) {
                    acc[rr][0] = *(float4*)(gp + rr * 512);
                    acc[rr][1] = *(float4*)(gp + rr * 512 + 4);
                }
                for (int k = 0; k < 32; k++) {
                    float4 la0 = *(const float4*)&Ls[k * LST + r0];
                    float4 la1 = *(const float4*)&Ls[k * LST + r0 + 4];
                    float4 u0  = *(const float4*)&R[k * RST + cc];
                    float4 u1  = *(const float4*)&R[k * RST + cc + 4];
                    float lv[8] = {la0.x, la0.y, la0.z, la0.w,
                                   la1.x, la1.y, la1.z, la1.w};
                    #pragma unroll
                    for (int rr = 0; rr < 8; rr++) {
                        acc[rr][0].x -= lv[rr] * u0.x;
                        acc[rr][0].y -= lv[rr] * u0.y;
                        acc[rr][0].z -= lv[rr] * u0.z;
                        acc[rr][0].w -= lv[rr] * u0.w;
                        acc[rr][1].x -= lv[rr] * u1.x;
                        acc[rr][1].y -= lv[rr] * u1.y;
                        acc[rr][1].z -= lv[rr] * u1.z;
                        acc[rr][1].w -= lv[rr] * u1.w;
                    }
                }
                #pragma unroll
                for (int rr = 0; rr < 8; rr++) {
                    *(float4*)(gp + rr * 512)     = acc[rr][0];
                    *(float4*)(gp + rr * 512 + 4) = acc[rr][1];
                }
            }
        }
        __syncthreads();
    }

    // ======== Phase B: blocked backward substitution U * M1 = Z ========
    for (int p = 7; p >= 0; p--) {
        int c0 = 32 * p;
        // load diag U block + current Z rows into LDS (reuse R as Rb, stride BST)
        R[ti * BST + tc] = A[(c0 + ti) * 512 + c0 + tc];
        for (int z = tc; z < 256; z += 32)
            R[ti * BST + 32 + z] = A[(c0 + ti) * 512 + 256 + z];
        // stage U-strip above block: Ls[k][i] = A[i][c0+k], i < c0
        for (int idx = tid; idx < c0 * 32; idx += 1024) {
            int i = idx >> 5, k = idx & 31;
            Ls[k * LST + i] = A[i * 512 + c0 + k];
        }
        __syncthreads();
        if (tid < 32) invd[tid] = 1.0f / R[tid * BST + tid];
        __syncthreads();
        // in-block reverse elimination (Z rows stay RAW; scale folded into coef)
        for (int j = 31; j >= 1; j--) {
            if (ti < j) {
                float coef = R[ti * BST + j] * invd[j];
                for (int z = tc; z < 256; z += 32)
                    R[ti * BST + 32 + z] -= coef * R[j * BST + 32 + z];
            }
            __syncthreads();
        }
        // scale -> X, write back M1 rows
        {
            float iv = invd[ti];
            for (int z = tc; z < 256; z += 32) {
                float x = R[ti * BST + 32 + z] * iv;
                R[ti * BST + 32 + z] = x;
                A[(c0 + ti) * 512 + 256 + z] = x;
            }
        }
        __syncthreads();
        // update rows above: Z[0:c0, :] -= U[0:c0, block] * X  (8x8 reg tiles)
        if (p > 0) {
            int tiles = (c0 >> 3) * 32;        // nct = 256/8 = 32
            for (int t = tid; t < tiles; t += 1024) {
                int rt = t >> 5, ct = t & 31;
                int r0 = rt << 3, z0 = ct << 3;
                float* gp = A + (size_t)r0 * 512 + 256 + z0;
                float4 acc[8][2];
                #pragma unroll
                for (int rr = 0; rr < 8; rr++) {
                    acc[rr][0] = *(float4*)(gp + rr * 512);
                    acc[rr][1] = *(float4*)(gp + rr * 512 + 4);
                }
                for (int k = 0; k < 32; k++) {
                    float4 la0 = *(const float4*)&Ls[k * LST + r0];
                    float4 la1 = *(const float4*)&Ls[k * LST + r0 + 4];
                    float4 x0  = *(const float4*)&R[k * BST + 32 + z0];
                    float4 x1  = *(const float4*)&R[k * BST + 32 + z0 + 4];
                    float lv[8] = {la0.x, la0.y, la0.z, la0.w,
                                   la1.x, la1.y, la1.z, la1.w};
                    #pragma unroll
                    for (int rr = 0; rr < 8; rr++) {
                        acc[rr][0].x -= lv[rr] * x0.x;
                        acc[rr][0].y -= lv[rr] * x0.y;
                        acc[rr][0].z -= lv[rr] * x0.z;
                        acc[rr][0].w -= lv[rr] * x0.w;
                        acc[rr][1].x -= lv[rr] * x1.x;
                        acc[rr][1].y -= lv[rr] * x1.y;
                        acc[rr][1].z -= lv[rr] * x1.z;
                        acc[rr][1].w -= lv[rr] * x1.w;
                    }
                }
                #pragma unroll
                for (int rr = 0; rr < 8; rr++) {
                    *(float4*)(gp + rr * 512)     = acc[rr][0];
                    *(float4*)(gp + rr * 512 + 4) = acc[rr][1];
                }
            }
        }
        __syncthreads();
    }
}

// ---------------- K6: W[f][e] = sum_y Yc[y][f] * M1[y][e] / 256 ----------------
__global__ __launch_bounds__(256) void k6_w(const float* __restrict__ Yc,
                                            const float* __restrict__ aug,
                                            float* __restrict__ W) {
    __shared__ float As[16][68];
    __shared__ float Bs[16][68];
    int tid = threadIdx.x;
    int m0 = blockIdx.x * 64, n0 = blockIdx.y * 64, b = blockIdx.z;
    const float* Ycb = Yc + (size_t)b * YD * ENSN;
    const float* augb = aug + (size_t)b * YD * 512;
    int tr = tid >> 4, tc = tid & 15;
    float acc[4][4];
    #pragma unroll
    for (int i = 0; i < 4; i++)
        #pragma unroll
        for (int j = 0; j < 4; j++) acc[i][j] = 0.f;
    int c = tid & 63, kr0 = tid >> 6;
    for (int k0 = 0; k0 < YD; k0 += 16) {
        #pragma unroll
        for (int p = 0; p < 4; p++) {
            int kk = kr0 + p * 4;
            As[kk][c] = Ycb[(k0 + kk) * ENSN + m0 + c];
            Bs[kk][c] = augb[(k0 + kk) * 512 + 256 + n0 + c];
        }
        __syncthreads();
        #pragma unroll
        for (int kk = 0; kk < 16; kk++) {
            float4 a = *(const float4*)&As[kk][tr * 4];
            float4 bb = *(const float4*)&Bs[kk][tc * 4];
            float af[4] = {a.x, a.y, a.z, a.w};
            float bf[4] = {bb.x, bb.y, bb.z, bb.w};
            #pragma unroll
            for (int i = 0; i < 4; i++)
                #pragma unroll
                for (int j = 0; j < 4; j++) acc[i][j] += af[i] * bf[j];
        }
        __syncthreads();
    }
    float* Wb = W + (size_t)b * ENSN * ENSN;
    #pragma unroll
    for (int i = 0; i < 4; i++)
        #pragma unroll
        for (int j = 0; j < 4; j++)
            Wb[(m0 + tr * 4 + i) * ENSN + n0 + tc * 4 + j] = acc[i][j] * (1.0f / ENSN);
}

// ---------------- K7: out[b,e,x] = Ens[b,e,x] + sum_f W[f][e]*(Ens[b,f,x]-x_m[b,x]) ----------------
__global__ __launch_bounds__(256) void k7_update(const float* __restrict__ E,
                                                 const float* __restrict__ W,
                                                 const float* __restrict__ xm,
                                                 float* __restrict__ out) {
    __shared__ float As[16][260];
    __shared__ float Bs[16][68];
    __shared__ float xs[64];
    int tid = threadIdx.x;
    int x0 = blockIdx.x * 64;
    int b = blockIdx.y;
    const float* Wb = W + (size_t)b * ENSN * ENSN;
    const float* Eb = E + (size_t)b * ENSN * XDIM;
    if (tid < 64) xs[tid] = xm[b * XDIM + x0 + tid];
    __syncthreads();
    int tr = tid >> 4, tc = tid & 15;
    float acc[16][4];
    #pragma unroll
    for (int i = 0; i < 16; i++)
        #pragma unroll
        for (int j = 0; j < 4; j++) acc[i][j] = 0.f;
    for (int k0 = 0; k0 < ENSN; k0 += 16) {
        #pragma unroll
        for (int p = 0; p < 16; p++)
            As[p][tid] = Wb[(k0 + p) * ENSN + tid];
        #pragma unroll
        for (int p = 0; p < 4; p++) {
            int kk = (tid >> 6) + p * 4;
            int cc = tid & 63;
            Bs[kk][cc] = Eb[(size_t)(k0 + kk) * XDIM + x0 + cc] - xs[cc];
        }
        __syncthreads();
        #pragma unroll
        for (int kk = 0; kk < 16; kk++) {
            float4 bv = *(const float4*)&Bs[kk][tc * 4];
            float bf[4] = {bv.x, bv.y, bv.z, bv.w};
            #pragma unroll
            for (int q = 0; q < 4; q++) {
                float4 av = *(const float4*)&As[kk][tr * 16 + q * 4];
                float af[4] = {av.x, av.y, av.z, av.w};
                #pragma unroll
                for (int c2 = 0; c2 < 4; c2++)
                    #pragma unroll
                    for (int j = 0; j < 4; j++)
                        acc[q * 4 + c2][j] += af[c2] * bf[j];
            }
        }
        __syncthreads();
    }
    #pragma unroll
    for (int i = 0; i < 16; i++) {
        int e = tr * 16 + i;
        size_t idx = (size_t)(b * ENSN + e) * XDIM + x0 + tc * 4;
        float4 ev = *(const float4*)&E[idx];
        float4 ov;
        ov.x = ev.x + acc[i][0];
        ov.y = ev.y + acc[i][1];
        ov.z = ev.z + acc[i][2];
        ov.w = ev.w + acc[i][3];
        *(float4*)&out[idx] = ov;
    }
}

extern "C" void kernel_launch(void* const* d_in, const int* in_sizes, int n_in,
                              void* d_out, int out_size, void* d_ws, size_t ws_size,
                              hipStream_t stream) {
    const float* Ens   = (const float*)d_in[0];  // [8,256,8192]
    const float* H     = (const float*)d_in[1];  // [8192,256]
    const float* ytm   = (const float*)d_in[2];  // [1,256]
    const float* ystd  = (const float*)d_in[3];  // [1,256]
    const float* noise = (const float*)d_in[4];  // [8,256,256]
    float* out = (float*)d_out;
    float* ws  = (float*)d_ws;

    float* Y   = ws + OFF_Y;
    float* Yc  = ws + OFF_YC;
    float* aug = ws + OFF_AUG;
    float* W   = ws + OFF_W;
    float* xm  = ws + OFF_XM;

    hipMemsetAsync(Y, 0, (size_t)2048 * 256 * sizeof(float), stream);

    k1_colmean<<<dim3(XDIM / 256, BATCH), 256, 0, stream>>>(Ens, xm);
    k2_ygemm<<<dim3(64, 8), 256, 0, stream>>>(Ens, H, Y);
    k3_center<<<dim3(BATCH), 256, 0, stream>>>(Y, ytm, ystd, noise, Yc, aug);
    k4_cyy<<<dim3(4, 4, BATCH), 256, 0, stream>>>(Yc, ystd, aug);
    k5_solve<<<dim3(BATCH), 1024, 0, stream>>>(aug);
    k6_w<<<dim3(4, 4, BATCH), 256, 0, stream>>>(Yc, aug, W);
    k7_update<<<dim3(XDIM / 64, BATCH), 256, 0, stream>>>(Ens, W, xm, out);
}

// Round 3
// 998.699 us; speedup vs baseline: 4.6407x; 1.3382x over previous
//
#include <hip/hip_runtime.h>

#define ENSN 256
#define XDIM 8192
#define YD 256
#define BATCH 8

// ws layout (float offsets)
#define OFF_Y   0          // [2048][256]            Y = Ens @ H
#define OFF_YC  524288     // [8][256(y)][256(e)]    Yc (transposed, centered)
#define OFF_AUG 1048576    // [8][256][512]          [A | innov] -> [U | M1]
#define OFF_W   2097152    // [8][256(f)][256(e)]    W = Yc^T M1 / 256
#define OFF_XM  2621440    // [8][8192]              x_m

// ---------------- K1: x_m[b][x] = mean_e Ens[b,e,x] ----------------
__global__ __launch_bounds__(256) void k1_colmean(const float* __restrict__ E,
                                                  float* __restrict__ xm) {
    int x = blockIdx.x * 256 + threadIdx.x;
    int b = blockIdx.y;
    const float* p = E + (size_t)b * ENSN * XDIM + x;
    float s = 0.f;
    #pragma unroll 8
    for (int e = 0; e < ENSN; e++) s += p[(size_t)e * XDIM];
    xm[b * XDIM + x] = s * (1.0f / ENSN);
}

// ---------------- K2: Y = E[2048x8192] @ H[8192x256] ----------------
// 128x64 tile, BK=16, split-K=8. grid (16,4,8) = 512 blocks, 256 thr.
// As stored transposed [k][m] (pad 132) -> all compute reads broadcast/2-way.
__global__ __launch_bounds__(256) void k2_ygemm(const float* __restrict__ E,
                                                const float* __restrict__ H,
                                                float* __restrict__ Y) {
    __shared__ __align__(16) float As[16][132];
    __shared__ __align__(16) float Bs[16][68];
    int tid = threadIdx.x;
    int m0 = blockIdx.x * 128;
    int n0 = blockIdx.y * 64;
    int kb0 = blockIdx.z * 1024;
    int tr = tid >> 4, tc = tid & 15;
    float acc0[4][4], acc1[4][4];
    #pragma unroll
    for (int i = 0; i < 4; i++)
        #pragma unroll
        for (int j = 0; j < 4; j++) { acc0[i][j] = 0.f; acc1[i][j] = 0.f; }
    int er = tid >> 2, ec = (tid & 3) * 4;   // E loader: 2 rows, 4 cols each
    int hr = tid >> 4, hc = (tid & 15) * 4;  // H loader: 1 float4
    for (int kb = kb0; kb < kb0 + 1024; kb += 16) {
        float4 e0 = *(const float4*)&E[(size_t)(m0 + er) * XDIM + kb + ec];
        float4 e1 = *(const float4*)&E[(size_t)(m0 + 64 + er) * XDIM + kb + ec];
        float4 hv = *(const float4*)&H[(size_t)(kb + hr) * YD + n0 + hc];
        As[ec + 0][er] = e0.x;  As[ec + 1][er] = e0.y;
        As[ec + 2][er] = e0.z;  As[ec + 3][er] = e0.w;
        As[ec + 0][64 + er] = e1.x;  As[ec + 1][64 + er] = e1.y;
        As[ec + 2][64 + er] = e1.z;  As[ec + 3][64 + er] = e1.w;
        *(float4*)&Bs[hr][hc] = hv;
        __syncthreads();
        #pragma unroll
        for (int kk = 0; kk < 16; kk++) {
            float4 a0 = *(const float4*)&As[kk][tr * 4];
            float4 a1 = *(const float4*)&As[kk][64 + tr * 4];
            float4 bv = *(const float4*)&Bs[kk][tc * 4];
            float af0[4] = {a0.x, a0.y, a0.z, a0.w};
            float af1[4] = {a1.x, a1.y, a1.z, a1.w};
            float bf[4]  = {bv.x, bv.y, bv.z, bv.w};
            #pragma unroll
            for (int i = 0; i < 4; i++)
                #pragma unroll
                for (int j = 0; j < 4; j++) {
                    acc0[i][j] += af0[i] * bf[j];
                    acc1[i][j] += af1[i] * bf[j];
                }
        }
        __syncthreads();
    }
    #pragma unroll
    for (int i = 0; i < 4; i++)
        #pragma unroll
        for (int j = 0; j < 4; j++) {
            atomicAdd(&Y[(m0 + tr * 4 + i) * YD + n0 + tc * 4 + j], acc0[i][j]);
            atomicAdd(&Y[(m0 + 64 + tr * 4 + i) * YD + n0 + tc * 4 + j], acc1[i][j]);
        }
}

// ---------------- K3: y_m, Yc[y][e], innov -> aug right half ----------------
__global__ __launch_bounds__(256) void k3_center(const float* __restrict__ Y,
                                                 const float* __restrict__ ytm,
                                                 const float* __restrict__ ystd,
                                                 const float* __restrict__ noise,
                                                 float* __restrict__ Yc,
                                                 float* __restrict__ aug) {
    int b = blockIdx.x, tid = threadIdx.x;
    __shared__ float ym[256], tms[256], s2[256];
    __shared__ float T[64][65];
    float s = 0.f;
    for (int e = 0; e < ENSN; e++) s += Y[(b * ENSN + e) * YD + tid];
    ym[tid] = s * (1.0f / ENSN);
    tms[tid] = ytm[tid];
    float sd = ystd[tid];
    s2[tid] = sd * sd;
    __syncthreads();
    for (int y0 = 0; y0 < YD; y0 += 64)
        for (int e0 = 0; e0 < ENSN; e0 += 64) {
            int yc = tid & 63, g0 = tid >> 6;
            #pragma unroll
            for (int p = 0; p < 16; p++) {
                int er = g0 + p * 4;
                T[er][yc] = Y[(b * ENSN + e0 + er) * YD + y0 + yc];
            }
            __syncthreads();
            int ec = tid & 63;
            #pragma unroll
            for (int p = 0; p < 16; p++) {
                int yr = g0 + p * 4;
                int y = y0 + yr, e = e0 + ec;
                float yv = T[ec][yr] - ym[y];
                Yc[(size_t)b * YD * ENSN + y * ENSN + e] = yv;
                aug[(size_t)b * YD * 512 + y * 512 + 256 + e] =
                    tms[y] - yv + noise[(size_t)b * YD * ENSN + y * ENSN + e] * s2[y];
            }
            __syncthreads();
        }
}

// ---------------- K4: A = Yc Yc^T / 256 + diag(std^2) -> aug left half ----------------
__global__ __launch_bounds__(256) void k4_cyy(const float* __restrict__ Yc,
                                              const float* __restrict__ ystd,
                                              float* __restrict__ aug) {
    __shared__ float As[16][68];
    __shared__ float Bs[16][68];
    int tid = threadIdx.x;
    int m0 = blockIdx.x * 64, n0 = blockIdx.y * 64, b = blockIdx.z;
    const float* Ycb = Yc + (size_t)b * YD * ENSN;
    int tr = tid >> 4, tc = tid & 15;
    float acc[4][4];
    #pragma unroll
    for (int i = 0; i < 4; i++)
        #pragma unroll
        for (int j = 0; j < 4; j++) acc[i][j] = 0.f;
    int al = tid & 15, am0 = tid >> 4;
    for (int k0 = 0; k0 < ENSN; k0 += 16) {
        #pragma unroll
        for (int p = 0; p < 4; p++) {
            int am = am0 + p * 16;
            As[al][am] = Ycb[(m0 + am) * ENSN + k0 + al];
            Bs[al][am] = Ycb[(n0 + am) * ENSN + k0 + al];
        }
        __syncthreads();
        #pragma unroll
        for (int kk = 0; kk < 16; kk++) {
            float4 a = *(const float4*)&As[kk][tr * 4];
            float4 bb = *(const float4*)&Bs[kk][tc * 4];
            float af[4] = {a.x, a.y, a.z, a.w};
            float bf[4] = {bb.x, bb.y, bb.z, bb.w};
            #pragma unroll
            for (int i = 0; i < 4; i++)
                #pragma unroll
                for (int j = 0; j < 4; j++) acc[i][j] += af[i] * bf[j];
        }
        __syncthreads();
    }
    float* augb = aug + (size_t)b * YD * 512;
    #pragma unroll
    for (int i = 0; i < 4; i++) {
        int u = m0 + tr * 4 + i;
        #pragma unroll
        for (int j = 0; j < 4; j++) {
            int v = n0 + tc * 4 + j;
            float val = acc[i][j] * (1.0f / ENSN);
            if (u == v) { float sv = ystd[u]; val += sv * sv; }
            augb[u * 512 + v] = val;
        }
    }
}

// ---------------- K5: blocked LU + solves, low-barrier version ----------------
// grid = 8 (batch), 1024 threads. aug[b] is 256x512 [A | innov] -> [U | M1].
// Per panel: wave0 in-register 32x32 LU (shfl, no barriers), col-parallel
// U12/RHS solve, row-parallel L21, tiled trailing GEMM. ~7 barriers/panel.
#define RST 484   // R stride: trailing cols (max 480); 484*4B = 16B aligned
#define LST 232   // Ls stride, layout [k][row]

__global__ __launch_bounds__(1024) void k5_solve(float* __restrict__ aug) {
    __shared__ __align__(16) float R[32 * RST];   // 62 KB: U12 / X block
    __shared__ __align__(16) float Ls[32 * LST];  // 29.7 KB: L21^T / U-strip
    __shared__ __align__(16) float Dg[32 * 33];   // diag block
    __shared__ float invd[32];
    int b = blockIdx.x, tid = threadIdx.x;
    float* A = aug + (size_t)b * 256 * 512;
    int r5 = tid >> 5, c5 = tid & 31;

    // ======== Phase A: blocked forward elimination on [A | Z] ========
    for (int p = 0; p < 8; p++) {
        int c0 = 32 * p;
        int W2 = 512 - c0 - 32;          // trailing width beyond panel (>=256)
        // stage diag block (coalesced)
        Dg[r5 * 33 + c5] = A[(c0 + r5) * 512 + c0 + c5];
        __syncthreads();
        // wave0: in-register LU of the 32x32 block (intra-wave order = sync)
        if (tid < 32) {
            float u[32];
            #pragma unroll
            for (int c = 0; c < 32; c++) u[c] = Dg[tid * 33 + c];
            for (int j = 0; j < 31; j++) {
                float pv = __shfl(u[j], j);
                float f = u[j] / pv;
                #pragma unroll
                for (int c = 0; c < 32; c++) {
                    if (c > j) {
                        float ujc = __shfl(u[c], j);
                        if (tid > j) u[c] -= f * ujc;
                    }
                }
                if (tid > j) u[j] = f;
            }
            #pragma unroll
            for (int c = 0; c < 32; c++) Dg[tid * 33 + c] = u[c];
            invd[tid] = 1.0f / u[tid];
        }
        __syncthreads();
        // write factored block back (Phase B reads U part)
        A[(c0 + r5) * 512 + c0 + c5] = Dg[r5 * 33 + c5];
        // col-parallel: U12/RHS = L11^-1 * A12  (L unit-diag; Dg broadcast)
        if (tid < W2) {
            int col = c0 + 32 + tid;
            float y[32];
            #pragma unroll
            for (int j = 0; j < 32; j++) {
                float s = A[(c0 + j) * 512 + col];
                #pragma unroll
                for (int m = 0; m < 32; m++)
                    if (m < j) s -= Dg[j * 33 + m] * y[m];
                y[j] = s;
            }
            #pragma unroll
            for (int j = 0; j < 32; j++) {
                A[(c0 + j) * 512 + col] = y[j];
                R[j * RST + tid] = y[j];
            }
        }
        // row-parallel: L21 = A21 * U11^-1
        int nb = 224 - c0;
        if (p < 7 && tid < nb) {
            int row = c0 + 32 + tid;
            float l[32];
            #pragma unroll
            for (int j = 0; j < 32; j++) {
                float s = A[row * 512 + c0 + j];
                #pragma unroll
                for (int m = 0; m < 32; m++)
                    if (m < j) s -= l[m] * Dg[m * 33 + j];
                l[j] = s * invd[j];
            }
            #pragma unroll
            for (int k = 0; k < 32; k++)
                Ls[k * LST + tid] = l[k];
        }
        __syncthreads();
        // trailing update: A22 -= L21 * U12 (8x8 reg tiles, incl RHS cols)
        if (p < 7) {
            int nct = W2 >> 3;
            int tiles = (nb >> 3) * nct;
            for (int t = tid; t < tiles; t += 1024) {
                int rt = t / nct, ct = t - rt * nct;
                int r0 = rt << 3, cc = ct << 3;
                float* gp = A + (size_t)(c0 + 32 + r0) * 512 + c0 + 32 + cc;
                float4 acc[8][2];
                #pragma unroll
                for (int rr = 0; rr < 8; rr++) {
                    acc[rr][0] = *(float4*)(gp + rr * 512);
                    acc[rr][1] = *(float4*)(gp + rr * 512 + 4);
                }
                for (int k = 0; k < 32; k++) {
                    float4 la0 = *(const float4*)&Ls[k * LST + r0];
                    float4 la1 = *(const float4*)&Ls[k * LST + r0 + 4];
                    float4 u0  = *(const float4*)&R[k * RST + cc];
                    float4 u1  = *(const float4*)&R[k * RST + cc + 4];
                    float lv[8] = {la0.x, la0.y, la0.z, la0.w,
                                   la1.x, la1.y, la1.z, la1.w};
                    #pragma unroll
                    for (int rr = 0; rr < 8; rr++) {
                        acc[rr][0].x -= lv[rr] * u0.x;
                        acc[rr][0].y -= lv[rr] * u0.y;
                        acc[rr][0].z -= lv[rr] * u0.z;
                        acc[rr][0].w -= lv[rr] * u0.w;
                        acc[rr][1].x -= lv[rr] * u1.x;
                        acc[rr][1].y -= lv[rr] * u1.y;
                        acc[rr][1].z -= lv[rr] * u1.z;
                        acc[rr][1].w -= lv[rr] * u1.w;
                    }
                }
                #pragma unroll
                for (int rr = 0; rr < 8; rr++) {
                    *(float4*)(gp + rr * 512)     = acc[rr][0];
                    *(float4*)(gp + rr * 512 + 4) = acc[rr][1];
                }
            }
        }
        __syncthreads();
    }

    // ======== Phase B: blocked backward substitution U * M1 = Z ========
    for (int p = 7; p >= 0; p--) {
        int c0 = 32 * p;
        // stage diag U block + U-strip above it
        Dg[r5 * 33 + c5] = A[(c0 + r5) * 512 + c0 + c5];
        for (int idx = tid; idx < c0 * 32; idx += 1024) {
            int i = idx >> 5, k = idx & 31;
            Ls[k * LST + i] = A[i * 512 + c0 + k];
        }
        __syncthreads();
        if (tid < 32) invd[tid] = 1.0f / Dg[tid * 33 + tid];
        __syncthreads();
        // col-parallel in-block back-solve (U upper part only)
        if (tid < 256) {
            float x[32];
            #pragma unroll
            for (int j = 31; j >= 0; j--) {
                float s = A[(c0 + j) * 512 + 256 + tid];
                #pragma unroll
                for (int m = 0; m < 32; m++)
                    if (m > j) s -= Dg[j * 33 + m] * x[m];
                x[j] = s * invd[j];
            }
            #pragma unroll
            for (int j = 0; j < 32; j++) {
                A[(c0 + j) * 512 + 256 + tid] = x[j];
                R[j * RST + tid] = x[j];
            }
        }
        __syncthreads();
        // update rows above: Z[0:c0,:] -= U[0:c0, block] * X
        if (p > 0) {
            int tiles = (c0 >> 3) * 32;        // 256/8 = 32 col tiles
            for (int t = tid; t < tiles; t += 1024) {
                int rt = t >> 5, ct = t & 31;
                int r0 = rt << 3, z0 = ct << 3;
                float* gp = A + (size_t)r0 * 512 + 256 + z0;
                float4 acc[8][2];
                #pragma unroll
                for (int rr = 0; rr < 8; rr++) {
                    acc[rr][0] = *(float4*)(gp + rr * 512);
                    acc[rr][1] = *(float4*)(gp + rr * 512 + 4);
                }
                for (int k = 0; k < 32; k++) {
                    float4 la0 = *(const float4*)&Ls[k * LST + r0];
                    float4 la1 = *(const float4*)&Ls[k * LST + r0 + 4];
                    float4 x0  = *(const float4*)&R[k * RST + z0];
                    float4 x1  = *(const float4*)&R[k * RST + z0 + 4];
                    float lv[8] = {la0.x, la0.y, la0.z, la0.w,
                                   la1.x, la1.y, la1.z, la1.w};
                    #pragma unroll
                    for (int rr = 0; rr < 8; rr++) {
                        acc[rr][0].x -= lv[rr] * x0.x;
                        acc[rr][0].y -= lv[rr] * x0.y;
                        acc[rr][0].z -= lv[rr] * x0.z;
                        acc[rr][0].w -= lv[rr] * x0.w;
                        acc[rr][1].x -= lv[rr] * x1.x;
                        acc[rr][1].y -= lv[rr] * x1.y;
                        acc[rr][1].z -= lv[rr] * x1.z;
                        acc[rr][1].w -= lv[rr] * x1.w;
                    }
                }
                #pragma unroll
                for (int rr = 0; rr < 8; rr++) {
                    *(float4*)(gp + rr * 512)     = acc[rr][0];
                    *(float4*)(gp + rr * 512 + 4) = acc[rr][1];
                }
            }
        }
        __syncthreads();
    }
}

// ---------------- K6: W[f][e] = sum_y Yc[y][f] * M1[y][e] / 256 ----------------
__global__ __launch_bounds__(256) void k6_w(const float* __restrict__ Yc,
                                            const float* __restrict__ aug,
                                            float* __restrict__ W) {
    __shared__ float As[16][68];
    __shared__ float Bs[16][68];
    int tid = threadIdx.x;
    int m0 = blockIdx.x * 64, n0 = blockIdx.y * 64, b = blockIdx.z;
    const float* Ycb = Yc + (size_t)b * YD * ENSN;
    const float* augb = aug + (size_t)b * YD * 512;
    int tr = tid >> 4, tc = tid & 15;
    float acc[4][4];
    #pragma unroll
    for (int i = 0; i < 4; i++)
        #pragma unroll
        for (int j = 0; j < 4; j++) acc[i][j] = 0.f;
    int c = tid & 63, kr0 = tid >> 6;
    for (int k0 = 0; k0 < YD; k0 += 16) {
        #pragma unroll
        for (int p = 0; p < 4; p++) {
            int kk = kr0 + p * 4;
            As[kk][c] = Ycb[(k0 + kk) * ENSN + m0 + c];
            Bs[kk][c] = augb[(k0 + kk) * 512 + 256 + n0 + c];
        }
        __syncthreads();
        #pragma unroll
        for (int kk = 0; kk < 16; kk++) {
            float4 a = *(const float4*)&As[kk][tr * 4];
            float4 bb = *(const float4*)&Bs[kk][tc * 4];
            float af[4] = {a.x, a.y, a.z, a.w};
            float bf[4] = {bb.x, bb.y, bb.z, bb.w};
            #pragma unroll
            for (int i = 0; i < 4; i++)
                #pragma unroll
                for (int j = 0; j < 4; j++) acc[i][j] += af[i] * bf[j];
        }
        __syncthreads();
    }
    float* Wb = W + (size_t)b * ENSN * ENSN;
    #pragma unroll
    for (int i = 0; i < 4; i++)
        #pragma unroll
        for (int j = 0; j < 4; j++)
            Wb[(m0 + tr * 4 + i) * ENSN + n0 + tc * 4 + j] = acc[i][j] * (1.0f / ENSN);
}

// ---------------- K7: out[b,e,x] = Ens[b,e,x] + sum_f W[f][e]*(Ens[b,f,x]-x_m[b,x]) ----------------
__global__ __launch_bounds__(256) void k7_update(const float* __restrict__ E,
                                                 const float* __restrict__ W,
                                                 const float* __restrict__ xm,
                                                 float* __restrict__ out) {
    __shared__ float As[16][260];
    __shared__ float Bs[16][68];
    __shared__ float xs[64];
    int tid = threadIdx.x;
    int x0 = blockIdx.x * 64;
    int b = blockIdx.y;
    const float* Wb = W + (size_t)b * ENSN * ENSN;
    const float* Eb = E + (size_t)b * ENSN * XDIM;
    if (tid < 64) xs[tid] = xm[b * XDIM + x0 + tid];
    __syncthreads();
    int tr = tid >> 4, tc = tid & 15;
    float acc[16][4];
    #pragma unroll
    for (int i = 0; i < 16; i++)
        #pragma unroll
        for (int j = 0; j < 4; j++) acc[i][j] = 0.f;
    for (int k0 = 0; k0 < ENSN; k0 += 16) {
        #pragma unroll
        for (int p = 0; p < 16; p++)
            As[p][tid] = Wb[(k0 + p) * ENSN + tid];
        #pragma unroll
        for (int p = 0; p < 4; p++) {
            int kk = (tid >> 6) + p * 4;
            int cc = tid & 63;
            Bs[kk][cc] = Eb[(size_t)(k0 + kk) * XDIM + x0 + cc] - xs[cc];
        }
        __syncthreads();
        #pragma unroll
        for (int kk = 0; kk < 16; kk++) {
            float4 bv = *(const float4*)&Bs[kk][tc * 4];
            float bf[4] = {bv.x, bv.y, bv.z, bv.w};
            #pragma unroll
            for (int q = 0; q < 4; q++) {
                float4 av = *(const float4*)&As[kk][tr * 16 + q * 4];
                float af[4] = {av.x, av.y, av.z, av.w};
                #pragma unroll
                for (int c2 = 0; c2 < 4; c2++)
                    #pragma unroll
                    for (int j = 0; j < 4; j++)
                        acc[q * 4 + c2][j] += af[c2] * bf[j];
            }
        }
        __syncthreads();
    }
    #pragma unroll
    for (int i = 0; i < 16; i++) {
        int e = tr * 16 + i;
        size_t idx = (size_t)(b * ENSN + e) * XDIM + x0 + tc * 4;
        float4 ev = *(const float4*)&E[idx];
        float4 ov;
        ov.x = ev.x + acc[i][0];
        ov.y = ev.y + acc[i][1];
        ov.z = ev.z + acc[i][2];
        ov.w = ev.w + acc[i][3];
        *(float4*)&out[idx] = ov;
    }
}

extern "C" void kernel_launch(void* const* d_in, const int* in_sizes, int n_in,
                              void* d_out, int out_size, void* d_ws, size_t ws_size,
                              hipStream_t stream) {
    const float* Ens   = (const float*)d_in[0];  // [8,256,8192]
    const float* H     = (const float*)d_in[1];  // [8192,256]
    const float* ytm   = (const float*)d_in[2];  // [1,256]
    const float* ystd  = (const float*)d_in[3];  // [1,256]
    const float* noise = (const float*)d_in[4];  // [8,256,256]
    float* out = (float*)d_out;
    float* ws  = (float*)d_ws;

    float* Y   = ws + OFF_Y;
    float* Yc  = ws + OFF_YC;
    float* aug = ws + OFF_AUG;
    float* W   = ws + OFF_W;
    float* xm  = ws + OFF_XM;

    hipMemsetAsync(Y, 0, (size_t)2048 * 256 * sizeof(float), stream);

    k1_colmean<<<dim3(XDIM / 256, BATCH), 256, 0, stream>>>(Ens, xm);
    k2_ygemm<<<dim3(16, 4, 8), 256, 0, stream>>>(Ens, H, Y);
    k3_center<<<dim3(BATCH), 256, 0, stream>>>(Y, ytm, ystd, noise, Yc, aug);
    k4_cyy<<<dim3(4, 4, BATCH), 256, 0, stream>>>(Yc, ystd, aug);
    k5_solve<<<dim3(BATCH), 1024, 0, stream>>>(aug);
    k6_w<<<dim3(4, 4, BATCH), 256, 0, stream>>>(Yc, aug, W);
    k7_update<<<dim3(XDIM / 64, BATCH), 256, 0, stream>>>(Ens, W, xm, out);
}